// Round 1
// 422.115 us; speedup vs baseline: 1.1550x; 1.1550x over previous
//
#include <hip/hip_runtime.h>
#include <hip/hip_bf16.h>
#include <math.h>

// LSD (local shape descriptors), 128^3, 8 labels, sigma=5, truncate=3 -> 31-tap kernel.
//
// Algebra: for label mask m, define G_{abc} = (k_a *_z)(k_b *_y)(k_c *_x) m with
//   k0(u)=w(u), k1(u)=u w(u), k2(u)=u^2 w(u)  (w = normalized gaussian).
// At a voxel with mass=G000>0, p=G100/mass, q=G010/mass, s=G001/mass:
//   mean_offset = 0.5 - {p,q,s}/(2 sigma);  cov_ab = (G../mass - ..)/sigma^2.
// Translation-invariant: coords input not needed. Masks disjoint -> each voxel
// takes only its own label's descriptor.
//
// R1: XCD z-slab swizzle (7.25x pass_y overfetch fixed).
// R3: register-tiled sliding-window convs, separate passes: 794 us.
// R4: y+x fused, 1024 blk x 128 thr, 16-row tile, T=4: FETCH 16 MB (works).
// R5/R6 FAILED: T=2 variants double A-request volume -> L2 reuse cliff
//     (FETCH 16 -> 220 MB). Lesson: keep T=4 / 128-thr / 1024-block geometry.
// R7: label batched into blockIdx.y, 4 dispatches total: 676 us.
// R8: SPARSE phase 2: compact seg==label voxels into LDS list, per-lane
//     31-tap x 10-output conv only at matches. bf16 B rows, zero pads.
//     487 us; pass_yx 346 us, WRITE_SIZE 427 MB (5.1x out), VALUBusy 32%.
// R9 (this round):
//   a) label-ADJACENT linearization: grid (8192), lin = g + 8*lab + 64*tile.
//      XCD = lin&7 unchanged; the 8 label blocks of one tile are 8 apart ->
//      co-resident -> partial 64B output lines merge in the XCD L2.
//      Predicted WRITE_SIZE 427 -> ~92 MB.
//   b) no memset: phase 2 writes EVERY voxel exactly once. seg outside [1,8]
//      is zero-written by the designated label (x&7)+1 (balanced, ~1/72).
//   c) 1-deep software pipeline of the sliding-window loads (pass_z and
//      pass_yx phase 1): FMA of row j overlaps load of row j+1.
//   d) LCAP 1024->512: LDS 33.8 -> 32 KB exactly -> 5 blocks/CU (was 4).

constexpr int NV = 128 * 128 * 128;
constexpr int SLICE = 128 * 128;
constexpr int R = 15;
constexpr int KL = 31;
constexpr int CSTRIDE = 160;            // u16: 16 pad + 128 data + 16 pad
constexpr int RSTRIDE = 6 * CSTRIDE + 8; // 968 u16; row stagger: 242w = 18 mod 32
constexpr int LCAP = 512;

struct Kw { float k0[KL]; float k1[KL]; float k2[KL]; };

__device__ __forceinline__ void fma4(float4& a, float w, const float4& b) {
    a.x = fmaf(w, b.x, a.x); a.y = fmaf(w, b.y, a.y);
    a.z = fmaf(w, b.z, a.z); a.w = fmaf(w, b.w, a.w);
}

__device__ __forceinline__ float4 load_mask4(const unsigned char* p, int lab) {
    unsigned int u = *(const unsigned int*)p;
    return make_float4(((u       ) & 255u) == (unsigned)lab ? 1.f : 0.f,
                       ((u >>  8 ) & 255u) == (unsigned)lab ? 1.f : 0.f,
                       ((u >> 16 ) & 255u) == (unsigned)lab ? 1.f : 0.f,
                       ((u >> 24 ) & 255u) == (unsigned)lab ? 1.f : 0.f);
}
__device__ __forceinline__ float4 load_mask4(const int* p, int lab) {
    int4 s = *(const int4*)p;
    return make_float4(s.x == lab ? 1.f : 0.f, s.y == lab ? 1.f : 0.f,
                       s.z == lab ? 1.f : 0.f, s.w == lab ? 1.f : 0.f);
}

__device__ __forceinline__ void seg_ld4(const unsigned char* p, int s[4]) {
    unsigned int u = *(const unsigned int*)p;
    s[0] = (int)(u & 255u); s[1] = (int)((u >> 8) & 255u);
    s[2] = (int)((u >> 16) & 255u); s[3] = (int)((u >> 24) & 255u);
}
__device__ __forceinline__ void seg_ld4(const int* p, int s[4]) {
    int4 v = *(const int4*)p;
    s[0] = v.x; s[1] = v.y; s[2] = v.z; s[3] = v.w;
}

__device__ __forceinline__ float bf_ld(const unsigned short* p) {
    return __uint_as_float(((unsigned int)(*p)) << 16);
}

// -------- pass_z: seg -> A[lab][3] (z-conv). grid (512, nlab), 256 thr. ----
template <typename ST>
__global__ __launch_bounds__(256) void pass_z_t(const ST* __restrict__ seg,
                                                float* __restrict__ A,
                                                int label0, size_t a_stride,
                                                Kw kw) {
    __shared__ float kp[3][37];           // zero-padded: kp[c][i] = k_c[i-3]
    if (threadIdx.x < 37) {
        int i = threadIdx.x, j = i - 3; bool ok = (j >= 0) && (j < KL);
        kp[0][i] = ok ? kw.k0[j] : 0.f;
        kp[1][i] = ok ? kw.k1[j] : 0.f;
        kp[2][i] = ok ? kw.k2[j] : 0.f;
    }
    __syncthreads();
    const int label = label0 + blockIdx.y;
    float* Ab = A + (size_t)blockIdx.y * a_stride;
    const int h = blockIdx.x, g = h & 7, l = h >> 3;       // 512 x-blocks
    const int tx = threadIdx.x & 31, ty = threadIdx.x >> 5;
    const int x0 = tx * 4;
    const int z0 = 16 * g + 4 * (l & 3);                   // XCD g owns z [16g,16g+16)
    const int y  = (l >> 2) * 8 + ty;

    float4 acc[4][3];
#pragma unroll
    for (int t = 0; t < 4; ++t)
#pragma unroll
        for (int c = 0; c < 3; ++c) acc[t][c] = make_float4(0.f, 0.f, 0.f, 0.f);

    // 1-deep pipelined sliding window: load j+1 while FMAing j.
    float4 cm = make_float4(0.f, 0.f, 0.f, 0.f);
    {
        int zz = z0 - R;
        if ((unsigned)zz < 128u)
            cm = load_mask4(seg + (zz * SLICE + y * 128 + x0), label);
    }
    for (int j = 0; j < 33; ++j) {                         // window: 4 outs + 30
        float4 nm = make_float4(0.f, 0.f, 0.f, 0.f);
        int zz = z0 + j + 1 - R;                           // uniform per wave
        if ((unsigned)zz < 128u)
            nm = load_mask4(seg + (zz * SLICE + y * 128 + x0), label);
#pragma unroll
        for (int t = 0; t < 4; ++t) {
            int i = j - t + 3;                             // padded weight index
            fma4(acc[t][0], kp[0][i], cm);
            fma4(acc[t][1], kp[1][i], cm);
            fma4(acc[t][2], kp[2][i], cm);
        }
        cm = nm;
    }
    {
        const int j = 33;
#pragma unroll
        for (int t = 0; t < 4; ++t) {
            int i = j - t + 3;
            fma4(acc[t][0], kp[0][i], cm);
            fma4(acc[t][1], kp[1][i], cm);
            fma4(acc[t][2], kp[2][i], cm);
        }
    }
#pragma unroll
    for (int t = 0; t < 4; ++t) {
        int base = (z0 + t) * SLICE + y * 128 + x0;
#pragma unroll
        for (int c = 0; c < 3; ++c)
            *(float4*)(Ab + (size_t)c * NV + base) = acc[t][c];
    }
}

// ---- per-voxel sparse x-conv + epilogue (B rows in bf16 LDS, zero-padded) -
__device__ __forceinline__ void do_voxel(const unsigned short* __restrict__ Bu,
                                         int rr, int x, int z0, int y0,
                                         float* __restrict__ out, const Kw& kw) {
    // value B(u) stored at row + c*CSTRIDE + 16 + u; window tap j reads
    // B(x-15+j) -> index x+1+j in [1,159) for x in [0,128). Pads are zero.
    const unsigned short* row = Bu + rr * RSTRIDE + (x + 1);
    float g000 = 0, g001 = 0, g002 = 0, g010 = 0, g011 = 0,
          g020 = 0, g100 = 0, g101 = 0, g110 = 0, g200 = 0;
#pragma unroll
    for (int j = 0; j < KL; ++j) {
        float w0 = kw.k0[j], w1 = kw.k1[j], w2 = kw.k2[j];
        float b0 = bf_ld(row + 0 * CSTRIDE + j);
        float b1 = bf_ld(row + 1 * CSTRIDE + j);
        float b2 = bf_ld(row + 2 * CSTRIDE + j);
        float b3 = bf_ld(row + 3 * CSTRIDE + j);
        float b4 = bf_ld(row + 4 * CSTRIDE + j);
        float b5 = bf_ld(row + 5 * CSTRIDE + j);
        g000 = fmaf(w0, b0, g000); g001 = fmaf(w1, b0, g001); g002 = fmaf(w2, b0, g002);
        g010 = fmaf(w0, b1, g010); g011 = fmaf(w1, b1, g011);
        g020 = fmaf(w0, b2, g020);
        g100 = fmaf(w0, b3, g100); g101 = fmaf(w1, b3, g101);
        g110 = fmaf(w0, b4, g110);
        g200 = fmaf(w0, b5, g200);
    }
    const int z2 = z0 + (rr >> 2), y2 = y0 + (rr & 3);
    const int v = (z2 * 128 + y2) * 128 + x;
    float mass = g000;
    float denom = (mass > 0.f) ? mass : 1.f;
    float inv = 1.f / denom;
    float p = g100 * inv, q = g010 * inv, s = g001 * inv;
    const float cs = 1.0f / 25.0f;                         // 1/sigma^2
    float o[10];
    o[0] = 0.5f - 0.1f * p;                                // 1/(2 sigma) = 0.1
    o[1] = 0.5f - 0.1f * q;
    o[2] = 0.5f - 0.1f * s;
    o[3] = (g200 * inv - p * p) * cs;
    o[4] = (g020 * inv - q * q) * cs;
    o[5] = (g002 * inv - s * s) * cs;
    o[6] = (g110 * inv - p * q) * cs;
    o[7] = (g011 * inv - q * s) * cs;
    o[8] = (g101 * inv - p * s) * cs;
    o[9] = mass;
#pragma unroll
    for (int c = 0; c < 10; ++c) {
        float val = fminf(fmaxf(o[c], 0.f), 1.f);
        out[(size_t)c * NV + v] = val;
    }
}

__device__ __forceinline__ void zero_voxel(int rr, int x, int z0, int y0,
                                           float* __restrict__ out) {
    const int z2 = z0 + (rr >> 2), y2 = y0 + (rr & 3);
    const int v = (z2 * 128 + y2) * 128 + x;
#pragma unroll
    for (int c = 0; c < 10; ++c) out[(size_t)c * NV + v] = 0.f;
}

// -------- pass_yx: A[lab][3] -> out. 128 thr. ------------------------------
// batched=1: grid (8192): lin = g + 8*lab + 64*tile  (labels co-resident ->
//            output lines merge in the XCD L2). batched=0: grid (1024), one
//            label (= label0) per dispatch.
// Phase 1 (R4 geometry): 16-row tile (4z x 4y), T=4 sliding y-outputs ->
// bf16 LDS rows with zero pads. Compaction: seg==label voxels AND this
// label's share of non-label voxels -> LDS list (atomicAdd).
// Phase 2: per-lane full conv at matched voxels, zero-store at zero entries.
// Every output voxel is written exactly once across the label set -> no memset.
template <typename ST>
__global__ __launch_bounds__(128) void pass_yx(const float* __restrict__ A,
                                               const ST* __restrict__ seg,
                                               float* __restrict__ out,
                                               int label0, size_t a_stride,
                                               Kw kw, int batched) {
    __shared__ float kp[3][37];
    __shared__ __align__(16) unsigned short Bu[16 * RSTRIDE]; // 30,976 B
    __shared__ unsigned short lst[LCAP];                      // 1 KB
    __shared__ int cnt;

    // zero Bs (pads must be exactly 0) + weights + counter
    {
        uint4 z4 = make_uint4(0, 0, 0, 0);
        uint4* b4 = (uint4*)Bu;                            // 16*968/8 = 1936
        for (int i = threadIdx.x; i < 1936; i += 128) b4[i] = z4;
    }
    if (threadIdx.x < 37) {
        int i = threadIdx.x, j = i - 3; bool ok = (j >= 0) && (j < KL);
        kp[0][i] = ok ? kw.k0[j] : 0.f;
        kp[1][i] = ok ? kw.k1[j] : 0.f;
        kp[2][i] = ok ? kw.k2[j] : 0.f;
    }
    if (threadIdx.x == 0) cnt = 0;
    __syncthreads();

    // decode: XCD = lin&7 always (hardware round-robin); batched path puts
    // the 8 labels of a tile at consecutive-by-8 linear ids.
    const int b = blockIdx.x;
    const int g = b & 7;
    int rest = b >> 3, labi = 0;
    if (batched) { labi = rest & 7; rest >>= 3; }
    const int l = rest;                                    // 0..127: tile in slab
    const int label = label0 + labi;
    const float* Ab = A + (size_t)labi * a_stride;

    const int tx = threadIdx.x & 31, tz = threadIdx.x >> 5; // tz 0..3
    const int x0 = tx * 4;
    const int z0 = 16 * g + 4 * (l & 3);                   // XCD g owns z slab
    const int y0 = (l >> 2) * 4;                           // 32 y-tiles
    const int zs = (z0 + tz) * SLICE;

    // ---- phase 1: y-conv, T=4 outputs sliding in registers, 1-deep pipe ----
    float4 acc[6][4];                                      // [ch][t]
#pragma unroll
    for (int c = 0; c < 6; ++c)
#pragma unroll
        for (int t = 0; t < 4; ++t) acc[c][t] = make_float4(0.f, 0.f, 0.f, 0.f);

    float4 c0 = make_float4(0.f, 0.f, 0.f, 0.f), c1 = c0, c2 = c0;
    {
        int yy = y0 - R;
        if ((unsigned)yy < 128u) {
            int base = zs + yy * 128 + x0;
            c0 = *(const float4*)(Ab + base);
            c1 = *(const float4*)(Ab + NV + base);
            c2 = *(const float4*)(Ab + 2 * NV + base);
        }
    }
    for (int j = 0; j < 33; ++j) {                         // window: 4 outs + 30
        float4 n0 = make_float4(0.f, 0.f, 0.f, 0.f), n1 = n0, n2 = n0;
        int yy = y0 + j + 1 - R;                           // uniform per block
        if ((unsigned)yy < 128u) {
            int base = zs + yy * 128 + x0;
            n0 = *(const float4*)(Ab + base);
            n1 = *(const float4*)(Ab + NV + base);
            n2 = *(const float4*)(Ab + 2 * NV + base);
        }
#pragma unroll
        for (int t = 0; t < 4; ++t) {
            int i = j - t + 3;
            float w0 = kp[0][i], w1 = kp[1][i], w2 = kp[2][i];
            fma4(acc[0][t], w0, c0);
            fma4(acc[1][t], w1, c0);
            fma4(acc[2][t], w2, c0);
            fma4(acc[3][t], w0, c1);
            fma4(acc[4][t], w1, c1);
            fma4(acc[5][t], w0, c2);
        }
        c0 = n0; c1 = n1; c2 = n2;
    }
    {
        const int j = 33;
#pragma unroll
        for (int t = 0; t < 4; ++t) {
            int i = j - t + 3;
            float w0 = kp[0][i], w1 = kp[1][i], w2 = kp[2][i];
            fma4(acc[0][t], w0, c0);
            fma4(acc[1][t], w1, c0);
            fma4(acc[2][t], w2, c0);
            fma4(acc[3][t], w0, c1);
            fma4(acc[4][t], w1, c1);
            fma4(acc[5][t], w0, c2);
        }
    }
#pragma unroll
    for (int t = 0; t < 4; ++t) {
        const int row = tz * 4 + t;                        // row = 4*zsub + ysub
#pragma unroll
        for (int c = 0; c < 6; ++c) {
            __hip_bfloat162 lo = __float22bfloat162_rn(make_float2(acc[c][t].x, acc[c][t].y));
            __hip_bfloat162 hi = __float22bfloat162_rn(make_float2(acc[c][t].z, acc[c][t].w));
            unsigned short* dst = Bu + row * RSTRIDE + c * CSTRIDE + 16 + x0;
            *reinterpret_cast<__hip_bfloat162*>(dst)     = lo;
            *reinterpret_cast<__hip_bfloat162*>(dst + 2) = hi;
        }
    }

    // ---- compaction: matched voxels + this label's share of non-label ----
    {
        const int rr = threadIdx.x >> 3, q0 = threadIdx.x & 7;
        const int z2 = z0 + (rr >> 2), y2 = y0 + (rr & 3);
        const int vrow = (z2 * 128 + y2) * 128;
#pragma unroll
        for (int k = 0; k < 4; ++k) {
            const int xb = 4 * (q0 + 8 * k);
            int s4[4];
            seg_ld4(seg + vrow + xb, s4);
#pragma unroll
            for (int t = 0; t < 4; ++t) {
                const int x = xb + t, sv = s4[t];
                const bool mt = (sv == label);
                const bool zt = !mt && (sv < 1 || sv > 8) &&
                                (((x & 7) + 1) == label);
                if (mt | zt) {
                    int pos = atomicAdd(&cnt, 1);
                    if (pos < LCAP)
                        lst[pos] = (unsigned short)((rr << 7) | x | (zt ? 0x8000 : 0));
                }
            }
        }
    }

    __syncthreads();

    // ---- phase 2: sparse x-conv + epilogue (or zero-store) ----
    const int total = cnt;
    if (total <= LCAP) {
        for (int e = threadIdx.x; e < total; e += 128) {
            int ent = lst[e];
            int rr = (ent >> 7) & 15, x = ent & 127;
            if (ent & 0x8000) zero_voxel(rr, x, z0, y0, out);
            else do_voxel(Bu, rr, x, z0, y0, out, kw);
        }
    } else {
        // adversarial-density fallback: dense masked sweep (same math)
        for (int e = threadIdx.x; e < 2048; e += 128) {
            int rr = e >> 7, x = e & 127;
            int z2 = z0 + (rr >> 2), y2 = y0 + (rr & 3);
            int sv = (int)seg[(z2 * 128 + y2) * 128 + x];
            if (sv == label)
                do_voxel(Bu, rr, x, z0, y0, out, kw);
            else if ((sv < 1 || sv > 8) && (((x & 7) + 1) == label))
                zero_voxel(rr, x, z0, y0, out);
        }
    }
}

__global__ __launch_bounds__(256) void seg_to_u8(const int* __restrict__ seg,
                                                 unsigned char* __restrict__ seg8) {
    const int t = blockIdx.x * 256 + threadIdx.x;          // 2048 blocks
    const int4 s = ((const int4*)seg)[t];
    ((uchar4*)seg8)[t] = make_uchar4((unsigned char)s.x, (unsigned char)s.y,
                                     (unsigned char)s.z, (unsigned char)s.w);
}

extern "C" void kernel_launch(void* const* d_in, const int* in_sizes, int n_in,
                              void* d_out, int out_size, void* d_ws, size_t ws_size,
                              hipStream_t stream) {
    const int* seg = (const int*)d_in[0];
    // d_in[1] (coords) unused: math is translation-invariant.
    float* out = (float*)d_out;
    float* A = (float*)d_ws;
    const size_t AVOL = (size_t)3 * NV;                    // floats per label

    Kw kw;
    double gg[KL], S = 0.0;
    for (int j = 0; j < KL; ++j) { double d = j - R; gg[j] = exp(-0.5 * d * d / 25.0); S += gg[j]; }
    for (int j = 0; j < KL; ++j) {
        double gn = gg[j] / S, d = j - R;
        kw.k0[j] = (float)gn;
        kw.k1[j] = (float)(-d * gn);   // conv kernel k1 evaluated at (Z - t) = -d
        kw.k2[j] = (float)(d * d * gn);
    }

    // No memset: pass_yx writes every output voxel exactly once across labels.

    const size_t need_all = 8 * AVOL * sizeof(float) + NV;  // A_all + seg8
    const size_t need_one = AVOL * sizeof(float) + NV;

    if (ws_size >= need_all) {
        // 3-dispatch path: labels batched, label-adjacent linearization.
        unsigned char* seg8 = (unsigned char*)(A + 8 * AVOL);
        seg_to_u8<<<dim3(2048), dim3(256), 0, stream>>>(seg, seg8);
        pass_z_t<unsigned char><<<dim3(512, 8), dim3(256), 0, stream>>>(
            seg8, A, 1, AVOL, kw);
        pass_yx<unsigned char><<<dim3(8192, 1), dim3(128), 0, stream>>>(
            A, seg8, out, 1, AVOL, kw, 1);
    } else if (ws_size >= need_one) {
        unsigned char* seg8 = (unsigned char*)(A + AVOL);
        seg_to_u8<<<dim3(2048), dim3(256), 0, stream>>>(seg, seg8);
        for (int label = 1; label <= 8; ++label) {
            pass_z_t<unsigned char><<<dim3(512, 1), dim3(256), 0, stream>>>(
                seg8, A, label, 0, kw);
            pass_yx<unsigned char><<<dim3(1024, 1), dim3(128), 0, stream>>>(
                A, seg8, out, label, 0, kw, 0);
        }
    } else {
        for (int label = 1; label <= 8; ++label) {
            pass_z_t<int><<<dim3(512, 1), dim3(256), 0, stream>>>(
                seg, A, label, 0, kw);
            pass_yx<int><<<dim3(1024, 1), dim3(128), 0, stream>>>(
                A, seg, out, label, 0, kw, 0);
        }
    }
}

// Round 2
// 412.436 us; speedup vs baseline: 1.1821x; 1.0235x over previous
//
#include <hip/hip_runtime.h>
#include <hip/hip_bf16.h>
#include <math.h>

// LSD (local shape descriptors), 128^3, 8 labels, sigma=5, truncate=3 -> 31-tap kernel.
//
// Algebra: for label mask m, define G_{abc} = (k_a *_z)(k_b *_y)(k_c *_x) m with
//   k0(u)=w(u), k1(u)=u w(u), k2(u)=u^2 w(u)  (w = normalized gaussian).
// At a voxel with mass=G000>0, p=G100/mass, q=G010/mass, s=G001/mass:
//   mean_offset = 0.5 - {p,q,s}/(2 sigma);  cov_ab = (G../mass - ..)/sigma^2.
// Translation-invariant: coords input not needed. Masks disjoint -> each voxel
// takes only its own label's descriptor.
//
// R1: XCD z-slab swizzle (7.25x pass_y overfetch fixed).
// R3: register-tiled sliding-window convs, separate passes: 794 us.
// R4: y+x fused, 1024 blk x 128 thr, 16-row tile, T=4: FETCH 16 MB (works).
// R5/R6 FAILED: T=2 variants double A-request volume -> L2 reuse cliff.
// R7: label batched into blockIdx.y, 4 dispatches total: 676 us.
// R8: SPARSE phase 2 (LDS list, bf16 B rows): 487 us; FETCH 121 MB (<A size
//     201 MB -> L3 absorbing), WRITE 417 MB (5.1x out).
// R9: label-adjacent linearization + no-memset + 1-deep pipelines + LCAP 512:
//     422 us. WRITE 417->248 (merge worked) but FETCH 121->400: 8 labels
//     co-resident -> A halo set 5.9 MB > 4 MB XCD L2 -> thrash. Also: total
//     stream (A 201 + out 84 + seg) just exceeds 256 MB L3.
// R10 (this round):
//   a) A stored bf16 (halves A traffic both sides; working set ~200 MB fits
//      L3 -> HBM fetch ~= compulsory; L3 merges partial-line out writes).
//      Unpack = 1 VALU op/value (shl / and-mask on pairs).
//   b) revert to tile-major grid (1024, nlab): the measured-good L2 layout
//      for A reuse (R8: 121 MB @ f32 -> expect ~60-80 @ bf16).
//   c) keep: no-memset full coverage, LCAP 512, pipelined windows, seg8.

constexpr int NV = 128 * 128 * 128;
constexpr int SLICE = 128 * 128;
constexpr int R = 15;
constexpr int KL = 31;
constexpr int CSTRIDE = 160;            // u16: 16 pad + 128 data + 16 pad
constexpr int RSTRIDE = 6 * CSTRIDE + 8; // 968 u16; row stagger: 242w = 18 mod 32
constexpr int LCAP = 512;

struct Kw { float k0[KL]; float k1[KL]; float k2[KL]; };

__device__ __forceinline__ void fma4(float4& a, float w, const float4& b) {
    a.x = fmaf(w, b.x, a.x); a.y = fmaf(w, b.y, a.y);
    a.z = fmaf(w, b.z, a.z); a.w = fmaf(w, b.w, a.w);
}

__device__ __forceinline__ float4 load_mask4(const unsigned char* p, int lab) {
    unsigned int u = *(const unsigned int*)p;
    return make_float4(((u       ) & 255u) == (unsigned)lab ? 1.f : 0.f,
                       ((u >>  8 ) & 255u) == (unsigned)lab ? 1.f : 0.f,
                       ((u >> 16 ) & 255u) == (unsigned)lab ? 1.f : 0.f,
                       ((u >> 24 ) & 255u) == (unsigned)lab ? 1.f : 0.f);
}
__device__ __forceinline__ float4 load_mask4(const int* p, int lab) {
    int4 s = *(const int4*)p;
    return make_float4(s.x == lab ? 1.f : 0.f, s.y == lab ? 1.f : 0.f,
                       s.z == lab ? 1.f : 0.f, s.w == lab ? 1.f : 0.f);
}

__device__ __forceinline__ void seg_ld4(const unsigned char* p, int s[4]) {
    unsigned int u = *(const unsigned int*)p;
    s[0] = (int)(u & 255u); s[1] = (int)((u >> 8) & 255u);
    s[2] = (int)((u >> 16) & 255u); s[3] = (int)((u >> 24) & 255u);
}
__device__ __forceinline__ void seg_ld4(const int* p, int s[4]) {
    int4 v = *(const int4*)p;
    s[0] = v.x; s[1] = v.y; s[2] = v.z; s[3] = v.w;
}

__device__ __forceinline__ float bf_ld(const unsigned short* p) {
    return __uint_as_float(((unsigned int)(*p)) << 16);
}

// 4 packed bf16 (as uint2) -> float4. 1 VALU op per value.
__device__ __forceinline__ float4 bf4_to_f4(uint2 u) {
    return make_float4(__uint_as_float(u.x << 16),
                       __uint_as_float(u.x & 0xFFFF0000u),
                       __uint_as_float(u.y << 16),
                       __uint_as_float(u.y & 0xFFFF0000u));
}

// -------- pass_z: seg -> A[lab][3] bf16 (z-conv). grid (512, nlab), 256 thr.
template <typename ST>
__global__ __launch_bounds__(256) void pass_z_t(const ST* __restrict__ seg,
                                                unsigned short* __restrict__ A,
                                                int label0, size_t a_stride,
                                                Kw kw) {
    __shared__ float kp[3][37];           // zero-padded: kp[c][i] = k_c[i-3]
    if (threadIdx.x < 37) {
        int i = threadIdx.x, j = i - 3; bool ok = (j >= 0) && (j < KL);
        kp[0][i] = ok ? kw.k0[j] : 0.f;
        kp[1][i] = ok ? kw.k1[j] : 0.f;
        kp[2][i] = ok ? kw.k2[j] : 0.f;
    }
    __syncthreads();
    const int label = label0 + blockIdx.y;
    unsigned short* Ab = A + (size_t)blockIdx.y * a_stride;
    const int h = blockIdx.x, g = h & 7, l = h >> 3;       // 512 x-blocks
    const int tx = threadIdx.x & 31, ty = threadIdx.x >> 5;
    const int x0 = tx * 4;
    const int z0 = 16 * g + 4 * (l & 3);                   // XCD g owns z [16g,16g+16)
    const int y  = (l >> 2) * 8 + ty;

    float4 acc[4][3];
#pragma unroll
    for (int t = 0; t < 4; ++t)
#pragma unroll
        for (int c = 0; c < 3; ++c) acc[t][c] = make_float4(0.f, 0.f, 0.f, 0.f);

    // 1-deep pipelined sliding window: load j+1 while FMAing j.
    float4 cm = make_float4(0.f, 0.f, 0.f, 0.f);
    {
        int zz = z0 - R;
        if ((unsigned)zz < 128u)
            cm = load_mask4(seg + (zz * SLICE + y * 128 + x0), label);
    }
    for (int j = 0; j < 33; ++j) {                         // window: 4 outs + 30
        float4 nm = make_float4(0.f, 0.f, 0.f, 0.f);
        int zz = z0 + j + 1 - R;                           // uniform per wave
        if ((unsigned)zz < 128u)
            nm = load_mask4(seg + (zz * SLICE + y * 128 + x0), label);
#pragma unroll
        for (int t = 0; t < 4; ++t) {
            int i = j - t + 3;                             // padded weight index
            fma4(acc[t][0], kp[0][i], cm);
            fma4(acc[t][1], kp[1][i], cm);
            fma4(acc[t][2], kp[2][i], cm);
        }
        cm = nm;
    }
    {
        const int j = 33;
#pragma unroll
        for (int t = 0; t < 4; ++t) {
            int i = j - t + 3;
            fma4(acc[t][0], kp[0][i], cm);
            fma4(acc[t][1], kp[1][i], cm);
            fma4(acc[t][2], kp[2][i], cm);
        }
    }
#pragma unroll
    for (int t = 0; t < 4; ++t) {
        int base = (z0 + t) * SLICE + y * 128 + x0;
#pragma unroll
        for (int c = 0; c < 3; ++c) {
            float4 v = acc[t][c];
            __hip_bfloat162 lo = __float22bfloat162_rn(make_float2(v.x, v.y));
            __hip_bfloat162 hi = __float22bfloat162_rn(make_float2(v.z, v.w));
            unsigned short* dst = Ab + (size_t)c * NV + base;
            *reinterpret_cast<__hip_bfloat162*>(dst)     = lo;
            *reinterpret_cast<__hip_bfloat162*>(dst + 2) = hi;
        }
    }
}

// ---- per-voxel sparse x-conv + epilogue (B rows in bf16 LDS, zero-padded) -
__device__ __forceinline__ void do_voxel(const unsigned short* __restrict__ Bu,
                                         int rr, int x, int z0, int y0,
                                         float* __restrict__ out, const Kw& kw) {
    // value B(u) stored at row + c*CSTRIDE + 16 + u; window tap j reads
    // B(x-15+j) -> index x+1+j in [1,159) for x in [0,128). Pads are zero.
    const unsigned short* row = Bu + rr * RSTRIDE + (x + 1);
    float g000 = 0, g001 = 0, g002 = 0, g010 = 0, g011 = 0,
          g020 = 0, g100 = 0, g101 = 0, g110 = 0, g200 = 0;
#pragma unroll
    for (int j = 0; j < KL; ++j) {
        float w0 = kw.k0[j], w1 = kw.k1[j], w2 = kw.k2[j];
        float b0 = bf_ld(row + 0 * CSTRIDE + j);
        float b1 = bf_ld(row + 1 * CSTRIDE + j);
        float b2 = bf_ld(row + 2 * CSTRIDE + j);
        float b3 = bf_ld(row + 3 * CSTRIDE + j);
        float b4 = bf_ld(row + 4 * CSTRIDE + j);
        float b5 = bf_ld(row + 5 * CSTRIDE + j);
        g000 = fmaf(w0, b0, g000); g001 = fmaf(w1, b0, g001); g002 = fmaf(w2, b0, g002);
        g010 = fmaf(w0, b1, g010); g011 = fmaf(w1, b1, g011);
        g020 = fmaf(w0, b2, g020);
        g100 = fmaf(w0, b3, g100); g101 = fmaf(w1, b3, g101);
        g110 = fmaf(w0, b4, g110);
        g200 = fmaf(w0, b5, g200);
    }
    const int z2 = z0 + (rr >> 2), y2 = y0 + (rr & 3);
    const int v = (z2 * 128 + y2) * 128 + x;
    float mass = g000;
    float denom = (mass > 0.f) ? mass : 1.f;
    float inv = 1.f / denom;
    float p = g100 * inv, q = g010 * inv, s = g001 * inv;
    const float cs = 1.0f / 25.0f;                         // 1/sigma^2
    float o[10];
    o[0] = 0.5f - 0.1f * p;                                // 1/(2 sigma) = 0.1
    o[1] = 0.5f - 0.1f * q;
    o[2] = 0.5f - 0.1f * s;
    o[3] = (g200 * inv - p * p) * cs;
    o[4] = (g020 * inv - q * q) * cs;
    o[5] = (g002 * inv - s * s) * cs;
    o[6] = (g110 * inv - p * q) * cs;
    o[7] = (g011 * inv - q * s) * cs;
    o[8] = (g101 * inv - p * s) * cs;
    o[9] = mass;
#pragma unroll
    for (int c = 0; c < 10; ++c) {
        float val = fminf(fmaxf(o[c], 0.f), 1.f);
        out[(size_t)c * NV + v] = val;
    }
}

__device__ __forceinline__ void zero_voxel(int rr, int x, int z0, int y0,
                                           float* __restrict__ out) {
    const int z2 = z0 + (rr >> 2), y2 = y0 + (rr & 3);
    const int v = (z2 * 128 + y2) * 128 + x;
#pragma unroll
    for (int c = 0; c < 10; ++c) out[(size_t)c * NV + v] = 0.f;
}

// -------- pass_yx: A[lab][3] bf16 -> out. grid (1024, nlab), 128 thr. ------
// Tile-major: blockIdx.x = tile (XCD = &7), blockIdx.y = label. This is the
// measured-good L2 layout for A reuse (R8). Phase 1 (R4 geometry): 16-row
// tile (4z x 4y), T=4 sliding y-outputs -> bf16 LDS rows with zero pads.
// Compaction: seg==label voxels AND this label's share of non-label voxels
// -> LDS list (atomicAdd). Phase 2: per-lane full conv at matched voxels,
// zero-store at zero entries. Every output voxel written exactly once across
// the label set -> no memset.
template <typename ST>
__global__ __launch_bounds__(128) void pass_yx(const unsigned short* __restrict__ A,
                                               const ST* __restrict__ seg,
                                               float* __restrict__ out,
                                               int label0, size_t a_stride,
                                               Kw kw) {
    __shared__ float kp[3][37];
    __shared__ __align__(16) unsigned short Bu[16 * RSTRIDE]; // 30,976 B
    __shared__ unsigned short lst[LCAP];                      // 1 KB
    __shared__ int cnt;

    // zero Bs (pads must be exactly 0) + weights + counter
    {
        uint4 z4 = make_uint4(0, 0, 0, 0);
        uint4* b4 = (uint4*)Bu;                            // 16*968/8 = 1936
        for (int i = threadIdx.x; i < 1936; i += 128) b4[i] = z4;
    }
    if (threadIdx.x < 37) {
        int i = threadIdx.x, j = i - 3; bool ok = (j >= 0) && (j < KL);
        kp[0][i] = ok ? kw.k0[j] : 0.f;
        kp[1][i] = ok ? kw.k1[j] : 0.f;
        kp[2][i] = ok ? kw.k2[j] : 0.f;
    }
    if (threadIdx.x == 0) cnt = 0;
    __syncthreads();

    const int labi = blockIdx.y;
    const int label = label0 + labi;
    const unsigned short* Ab = A + (size_t)labi * a_stride;
    const int h = blockIdx.x, g = h & 7, l = h >> 3;       // 1024 x-blocks
    const int tx = threadIdx.x & 31, tz = threadIdx.x >> 5; // tz 0..3
    const int x0 = tx * 4;
    const int z0 = 16 * g + 4 * (l & 3);                   // XCD g owns z slab
    const int y0 = (l >> 2) * 4;                           // 32 y-tiles
    const int zs = (z0 + tz) * SLICE;

    // ---- phase 1: y-conv, T=4 outputs sliding in registers, 1-deep pipe ----
    float4 acc[6][4];                                      // [ch][t]
#pragma unroll
    for (int c = 0; c < 6; ++c)
#pragma unroll
        for (int t = 0; t < 4; ++t) acc[c][t] = make_float4(0.f, 0.f, 0.f, 0.f);

    uint2 r0 = make_uint2(0u, 0u), r1 = r0, r2 = r0;       // packed bf16 x4
    {
        int yy = y0 - R;
        if ((unsigned)yy < 128u) {
            int base = zs + yy * 128 + x0;
            r0 = *(const uint2*)(Ab + base);
            r1 = *(const uint2*)(Ab + NV + base);
            r2 = *(const uint2*)(Ab + 2 * NV + base);
        }
    }
    for (int j = 0; j < 33; ++j) {                         // window: 4 outs + 30
        uint2 n0 = make_uint2(0u, 0u), n1 = n0, n2 = n0;
        int yy = y0 + j + 1 - R;                           // uniform per block
        if ((unsigned)yy < 128u) {
            int base = zs + yy * 128 + x0;
            n0 = *(const uint2*)(Ab + base);
            n1 = *(const uint2*)(Ab + NV + base);
            n2 = *(const uint2*)(Ab + 2 * NV + base);
        }
        float4 c0 = bf4_to_f4(r0), c1 = bf4_to_f4(r1), c2 = bf4_to_f4(r2);
#pragma unroll
        for (int t = 0; t < 4; ++t) {
            int i = j - t + 3;
            float w0 = kp[0][i], w1 = kp[1][i], w2 = kp[2][i];
            fma4(acc[0][t], w0, c0);
            fma4(acc[1][t], w1, c0);
            fma4(acc[2][t], w2, c0);
            fma4(acc[3][t], w0, c1);
            fma4(acc[4][t], w1, c1);
            fma4(acc[5][t], w0, c2);
        }
        r0 = n0; r1 = n1; r2 = n2;
    }
    {
        const int j = 33;
        float4 c0 = bf4_to_f4(r0), c1 = bf4_to_f4(r1), c2 = bf4_to_f4(r2);
#pragma unroll
        for (int t = 0; t < 4; ++t) {
            int i = j - t + 3;
            float w0 = kp[0][i], w1 = kp[1][i], w2 = kp[2][i];
            fma4(acc[0][t], w0, c0);
            fma4(acc[1][t], w1, c0);
            fma4(acc[2][t], w2, c0);
            fma4(acc[3][t], w0, c1);
            fma4(acc[4][t], w1, c1);
            fma4(acc[5][t], w0, c2);
        }
    }
#pragma unroll
    for (int t = 0; t < 4; ++t) {
        const int row = tz * 4 + t;                        // row = 4*zsub + ysub
#pragma unroll
        for (int c = 0; c < 6; ++c) {
            __hip_bfloat162 lo = __float22bfloat162_rn(make_float2(acc[c][t].x, acc[c][t].y));
            __hip_bfloat162 hi = __float22bfloat162_rn(make_float2(acc[c][t].z, acc[c][t].w));
            unsigned short* dst = Bu + row * RSTRIDE + c * CSTRIDE + 16 + x0;
            *reinterpret_cast<__hip_bfloat162*>(dst)     = lo;
            *reinterpret_cast<__hip_bfloat162*>(dst + 2) = hi;
        }
    }

    // ---- compaction: matched voxels + this label's share of non-label ----
    {
        const int rr = threadIdx.x >> 3, q0 = threadIdx.x & 7;
        const int z2 = z0 + (rr >> 2), y2 = y0 + (rr & 3);
        const int vrow = (z2 * 128 + y2) * 128;
#pragma unroll
        for (int k = 0; k < 4; ++k) {
            const int xb = 4 * (q0 + 8 * k);
            int s4[4];
            seg_ld4(seg + vrow + xb, s4);
#pragma unroll
            for (int t = 0; t < 4; ++t) {
                const int x = xb + t, sv = s4[t];
                const bool mt = (sv == label);
                const bool zt = !mt && (sv < 1 || sv > 8) &&
                                (((x & 7) + 1) == label);
                if (mt | zt) {
                    int pos = atomicAdd(&cnt, 1);
                    if (pos < LCAP)
                        lst[pos] = (unsigned short)((rr << 7) | x | (zt ? 0x8000 : 0));
                }
            }
        }
    }

    __syncthreads();

    // ---- phase 2: sparse x-conv + epilogue (or zero-store) ----
    const int total = cnt;
    if (total <= LCAP) {
        for (int e = threadIdx.x; e < total; e += 128) {
            int ent = lst[e];
            int rr = (ent >> 7) & 15, x = ent & 127;
            if (ent & 0x8000) zero_voxel(rr, x, z0, y0, out);
            else do_voxel(Bu, rr, x, z0, y0, out, kw);
        }
    } else {
        // adversarial-density fallback: dense masked sweep (same math)
        for (int e = threadIdx.x; e < 2048; e += 128) {
            int rr = e >> 7, x = e & 127;
            int z2 = z0 + (rr >> 2), y2 = y0 + (rr & 3);
            int sv = (int)seg[(z2 * 128 + y2) * 128 + x];
            if (sv == label)
                do_voxel(Bu, rr, x, z0, y0, out, kw);
            else if ((sv < 1 || sv > 8) && (((x & 7) + 1) == label))
                zero_voxel(rr, x, z0, y0, out);
        }
    }
}

__global__ __launch_bounds__(256) void seg_to_u8(const int* __restrict__ seg,
                                                 unsigned char* __restrict__ seg8) {
    const int t = blockIdx.x * 256 + threadIdx.x;          // 2048 blocks
    const int4 s = ((const int4*)seg)[t];
    ((uchar4*)seg8)[t] = make_uchar4((unsigned char)s.x, (unsigned char)s.y,
                                     (unsigned char)s.z, (unsigned char)s.w);
}

extern "C" void kernel_launch(void* const* d_in, const int* in_sizes, int n_in,
                              void* d_out, int out_size, void* d_ws, size_t ws_size,
                              hipStream_t stream) {
    const int* seg = (const int*)d_in[0];
    // d_in[1] (coords) unused: math is translation-invariant.
    float* out = (float*)d_out;
    unsigned short* A = (unsigned short*)d_ws;             // bf16 A planes
    const size_t AVOL = (size_t)3 * NV;                    // u16 elements/label

    Kw kw;
    double gg[KL], S = 0.0;
    for (int j = 0; j < KL; ++j) { double d = j - R; gg[j] = exp(-0.5 * d * d / 25.0); S += gg[j]; }
    for (int j = 0; j < KL; ++j) {
        double gn = gg[j] / S, d = j - R;
        kw.k0[j] = (float)gn;
        kw.k1[j] = (float)(-d * gn);   // conv kernel k1 evaluated at (Z - t) = -d
        kw.k2[j] = (float)(d * d * gn);
    }

    // No memset: pass_yx writes every output voxel exactly once across labels.

    const size_t need_all = 8 * AVOL * sizeof(unsigned short) + NV;  // A_all + seg8
    const size_t need_one = AVOL * sizeof(unsigned short) + NV;

    if (ws_size >= need_all) {
        // 3-dispatch path: labels batched in blockIdx.y, tile-major in x.
        unsigned char* seg8 = (unsigned char*)d_ws + 8 * AVOL * sizeof(unsigned short);
        seg_to_u8<<<dim3(2048), dim3(256), 0, stream>>>(seg, seg8);
        pass_z_t<unsigned char><<<dim3(512, 8), dim3(256), 0, stream>>>(
            seg8, A, 1, AVOL, kw);
        pass_yx<unsigned char><<<dim3(1024, 8), dim3(128), 0, stream>>>(
            A, seg8, out, 1, AVOL, kw);
    } else if (ws_size >= need_one) {
        unsigned char* seg8 = (unsigned char*)d_ws + AVOL * sizeof(unsigned short);
        seg_to_u8<<<dim3(2048), dim3(256), 0, stream>>>(seg, seg8);
        for (int label = 1; label <= 8; ++label) {
            pass_z_t<unsigned char><<<dim3(512, 1), dim3(256), 0, stream>>>(
                seg8, A, label, 0, kw);
            pass_yx<unsigned char><<<dim3(1024, 1), dim3(128), 0, stream>>>(
                A, seg8, out, label, 0, kw);
        }
    } else {
        for (int label = 1; label <= 8; ++label) {
            pass_z_t<int><<<dim3(512, 1), dim3(256), 0, stream>>>(
                seg, A, label, 0, kw);
            pass_yx<int><<<dim3(1024, 1), dim3(128), 0, stream>>>(
                A, seg, out, label, 0, kw);
        }
    }
}

// Round 3
// 407.491 us; speedup vs baseline: 1.1964x; 1.0121x over previous
//
#include <hip/hip_runtime.h>
#include <hip/hip_bf16.h>
#include <math.h>

// LSD (local shape descriptors), 128^3, 8 labels, sigma=5, truncate=3 -> 31-tap kernel.
//
// Algebra: for label mask m, define G_{abc} = (k_a *_z)(k_b *_y)(k_c *_x) m with
//   k0(u)=w(u), k1(u)=u w(u), k2(u)=u^2 w(u)  (w = normalized gaussian).
// At a voxel with mass=G000>0, p=G100/mass, q=G010/mass, s=G001/mass:
//   mean_offset = 0.5 - {p,q,s}/(2 sigma);  cov_ab = (G../mass - ..)/sigma^2.
// Translation-invariant: coords input not needed. Masks disjoint.
//
// R4: y+x fused, 1024 blk x 128 thr, 16-row tile, T=4: FETCH 16 MB (works).
// R5/R6 FAILED: T=2 variants double A-request volume -> L2 reuse cliff.
// R7: label batched into blockIdx.y: 676 us.
// R8: SPARSE phase 2 (LDS list, bf16 B rows): 487 us.
// R9: label-adjacent order + no-memset + 1-deep pipe: 422. WRITE 417->248
//     but FETCH 121->400 (A f32 thrash of XCD L2).
// R10: bf16 A + tile-major: 412. FETCH 400->61 (A now L2-resident) but
//     WRITE 248->465 (labels separated in time again).
//     KEY: R9 vs R10 traffic differs hugely, dur ~equal -> NOT BW-bound;
//     latency/issue-bound (VALUBusy 44%, occ 21%, HBM 23% of peak).
// R11 (this round): attack latency/issue, keep R10 traffic config.
//   a) 2-deep software pipeline in both conv windows (load j+2 during j).
//   b) ballot-based compaction: 16 per-lane LDS atomics -> 1 atomic/wave/step
//      (+ popcll prefix). Order in the list is irrelevant.
//   c) pre-issue compaction seg loads before phase 1 (packed u32 regs).
//   d) 8B combined bf16 stores (pass_z epilogue, Bu LDS writes).

constexpr int NV = 128 * 128 * 128;
constexpr int SLICE = 128 * 128;
constexpr int R = 15;
constexpr int KL = 31;
constexpr int CSTRIDE = 160;            // u16: 16 pad + 128 data + 16 pad
constexpr int RSTRIDE = 6 * CSTRIDE + 8; // 968 u16; row stagger: 242w = 18 mod 32
constexpr int LCAP = 512;

struct Kw { float k0[KL]; float k1[KL]; float k2[KL]; };

__device__ __forceinline__ void fma4(float4& a, float w, const float4& b) {
    a.x = fmaf(w, b.x, a.x); a.y = fmaf(w, b.y, a.y);
    a.z = fmaf(w, b.z, a.z); a.w = fmaf(w, b.w, a.w);
}

__device__ __forceinline__ float4 load_mask4(const unsigned char* p, int lab) {
    unsigned int u = *(const unsigned int*)p;
    return make_float4(((u       ) & 255u) == (unsigned)lab ? 1.f : 0.f,
                       ((u >>  8 ) & 255u) == (unsigned)lab ? 1.f : 0.f,
                       ((u >> 16 ) & 255u) == (unsigned)lab ? 1.f : 0.f,
                       ((u >> 24 ) & 255u) == (unsigned)lab ? 1.f : 0.f);
}
__device__ __forceinline__ float4 load_mask4(const int* p, int lab) {
    int4 s = *(const int4*)p;
    return make_float4(s.x == lab ? 1.f : 0.f, s.y == lab ? 1.f : 0.f,
                       s.z == lab ? 1.f : 0.f, s.w == lab ? 1.f : 0.f);
}

// 4 seg values packed into one u32 (low bytes). Labels are 1..8 so the
// byte-truncation aliasing matches the existing seg_to_u8 semantics.
__device__ __forceinline__ unsigned seg_pack4(const unsigned char* p) {
    return *(const unsigned int*)p;
}
__device__ __forceinline__ unsigned seg_pack4(const int* p) {
    int4 v = *(const int4*)p;
    return (unsigned)(v.x & 255) | ((unsigned)(v.y & 255) << 8) |
           ((unsigned)(v.z & 255) << 16) | ((unsigned)(v.w & 255) << 24);
}

__device__ __forceinline__ float bf_ld(const unsigned short* p) {
    return __uint_as_float(((unsigned int)(*p)) << 16);
}

// 4 packed bf16 (as uint2) -> float4. 1 VALU op per value.
__device__ __forceinline__ float4 bf4_to_f4(uint2 u) {
    return make_float4(__uint_as_float(u.x << 16),
                       __uint_as_float(u.x & 0xFFFF0000u),
                       __uint_as_float(u.y << 16),
                       __uint_as_float(u.y & 0xFFFF0000u));
}

__device__ __forceinline__ unsigned pack_bf2(float a, float b) {
    __hip_bfloat162 h = __float22bfloat162_rn(make_float2(a, b));
    return *reinterpret_cast<unsigned*>(&h);
}

// -------- pass_z: seg -> A[lab][3] bf16 (z-conv). grid (512, nlab), 256 thr.
template <typename ST>
__global__ __launch_bounds__(256) void pass_z_t(const ST* __restrict__ seg,
                                                unsigned short* __restrict__ A,
                                                int label0, size_t a_stride,
                                                Kw kw) {
    __shared__ float kp[3][37];           // zero-padded: kp[c][i] = k_c[i-3]
    if (threadIdx.x < 37) {
        int i = threadIdx.x, j = i - 3; bool ok = (j >= 0) && (j < KL);
        kp[0][i] = ok ? kw.k0[j] : 0.f;
        kp[1][i] = ok ? kw.k1[j] : 0.f;
        kp[2][i] = ok ? kw.k2[j] : 0.f;
    }
    __syncthreads();
    const int label = label0 + blockIdx.y;
    unsigned short* Ab = A + (size_t)blockIdx.y * a_stride;
    const int h = blockIdx.x, g = h & 7, l = h >> 3;       // 512 x-blocks
    const int tx = threadIdx.x & 31, ty = threadIdx.x >> 5;
    const int x0 = tx * 4;
    const int z0 = 16 * g + 4 * (l & 3);                   // XCD g owns z [16g,16g+16)
    const int y  = (l >> 2) * 8 + ty;

    float4 acc[4][3];
#pragma unroll
    for (int t = 0; t < 4; ++t)
#pragma unroll
        for (int c = 0; c < 3; ++c) acc[t][c] = make_float4(0.f, 0.f, 0.f, 0.f);

    // 2-deep pipelined sliding window: load j+2 while FMAing j.
    float4 cm = make_float4(0.f, 0.f, 0.f, 0.f), nm = cm;
    {
        int zz = z0 - R;
        if ((unsigned)zz < 128u)
            cm = load_mask4(seg + (zz * SLICE + y * 128 + x0), label);
        int zn = z0 + 1 - R;
        if ((unsigned)zn < 128u)
            nm = load_mask4(seg + (zn * SLICE + y * 128 + x0), label);
    }
    for (int j = 0; j < 34; ++j) {                         // window: 4 outs + 30
        float4 fm = make_float4(0.f, 0.f, 0.f, 0.f);
        int zz = z0 + j + 2 - R;                           // uniform per wave
        if (j < 32 && (unsigned)zz < 128u)
            fm = load_mask4(seg + (zz * SLICE + y * 128 + x0), label);
#pragma unroll
        for (int t = 0; t < 4; ++t) {
            int i = j - t + 3;                             // padded weight index
            fma4(acc[t][0], kp[0][i], cm);
            fma4(acc[t][1], kp[1][i], cm);
            fma4(acc[t][2], kp[2][i], cm);
        }
        cm = nm; nm = fm;
    }
#pragma unroll
    for (int t = 0; t < 4; ++t) {
        int base = (z0 + t) * SLICE + y * 128 + x0;
#pragma unroll
        for (int c = 0; c < 3; ++c) {
            float4 v = acc[t][c];
            uint2 pv = make_uint2(pack_bf2(v.x, v.y), pack_bf2(v.z, v.w));
            *reinterpret_cast<uint2*>(Ab + (size_t)c * NV + base) = pv;
        }
    }
}

// ---- per-voxel sparse x-conv + epilogue (B rows in bf16 LDS, zero-padded) -
__device__ __forceinline__ void do_voxel(const unsigned short* __restrict__ Bu,
                                         int rr, int x, int z0, int y0,
                                         float* __restrict__ out, const Kw& kw) {
    // value B(u) stored at row + c*CSTRIDE + 16 + u; window tap j reads
    // B(x-15+j) -> index x+1+j in [1,159) for x in [0,128). Pads are zero.
    const unsigned short* row = Bu + rr * RSTRIDE + (x + 1);
    float g000 = 0, g001 = 0, g002 = 0, g010 = 0, g011 = 0,
          g020 = 0, g100 = 0, g101 = 0, g110 = 0, g200 = 0;
#pragma unroll
    for (int j = 0; j < KL; ++j) {
        float w0 = kw.k0[j], w1 = kw.k1[j], w2 = kw.k2[j];
        float b0 = bf_ld(row + 0 * CSTRIDE + j);
        float b1 = bf_ld(row + 1 * CSTRIDE + j);
        float b2 = bf_ld(row + 2 * CSTRIDE + j);
        float b3 = bf_ld(row + 3 * CSTRIDE + j);
        float b4 = bf_ld(row + 4 * CSTRIDE + j);
        float b5 = bf_ld(row + 5 * CSTRIDE + j);
        g000 = fmaf(w0, b0, g000); g001 = fmaf(w1, b0, g001); g002 = fmaf(w2, b0, g002);
        g010 = fmaf(w0, b1, g010); g011 = fmaf(w1, b1, g011);
        g020 = fmaf(w0, b2, g020);
        g100 = fmaf(w0, b3, g100); g101 = fmaf(w1, b3, g101);
        g110 = fmaf(w0, b4, g110);
        g200 = fmaf(w0, b5, g200);
    }
    const int z2 = z0 + (rr >> 2), y2 = y0 + (rr & 3);
    const int v = (z2 * 128 + y2) * 128 + x;
    float mass = g000;
    float denom = (mass > 0.f) ? mass : 1.f;
    float inv = 1.f / denom;
    float p = g100 * inv, q = g010 * inv, s = g001 * inv;
    const float cs = 1.0f / 25.0f;                         // 1/sigma^2
    float o[10];
    o[0] = 0.5f - 0.1f * p;                                // 1/(2 sigma) = 0.1
    o[1] = 0.5f - 0.1f * q;
    o[2] = 0.5f - 0.1f * s;
    o[3] = (g200 * inv - p * p) * cs;
    o[4] = (g020 * inv - q * q) * cs;
    o[5] = (g002 * inv - s * s) * cs;
    o[6] = (g110 * inv - p * q) * cs;
    o[7] = (g011 * inv - q * s) * cs;
    o[8] = (g101 * inv - p * s) * cs;
    o[9] = mass;
#pragma unroll
    for (int c = 0; c < 10; ++c) {
        float val = fminf(fmaxf(o[c], 0.f), 1.f);
        out[(size_t)c * NV + v] = val;
    }
}

__device__ __forceinline__ void zero_voxel(int rr, int x, int z0, int y0,
                                           float* __restrict__ out) {
    const int z2 = z0 + (rr >> 2), y2 = y0 + (rr & 3);
    const int v = (z2 * 128 + y2) * 128 + x;
#pragma unroll
    for (int c = 0; c < 10; ++c) out[(size_t)c * NV + v] = 0.f;
}

// -------- pass_yx: A[lab][3] bf16 -> out. grid (1024, nlab), 128 thr. ------
// Tile-major: blockIdx.x = tile (XCD = &7), blockIdx.y = label (the
// measured-good L2 layout for short A-load latency; FETCH 61 MB).
// Phase 1: 16-row tile (4z x 4y), T=4 sliding y-outputs, 2-deep pipeline ->
// bf16 LDS rows with zero pads. Compaction: ballot-based (1 atomic/wave/step).
// Phase 2: per-lane full conv at matched voxels, zero-store at designated
// non-label voxels. Every output voxel written exactly once -> no memset.
template <typename ST>
__global__ __launch_bounds__(128) void pass_yx(const unsigned short* __restrict__ A,
                                               const ST* __restrict__ seg,
                                               float* __restrict__ out,
                                               int label0, size_t a_stride,
                                               Kw kw) {
    __shared__ float kp[3][37];
    __shared__ __align__(16) unsigned short Bu[16 * RSTRIDE]; // 30,976 B
    __shared__ unsigned short lst[LCAP];                      // 1 KB
    __shared__ int cnt;

    // zero Bs (pads must be exactly 0) + weights + counter
    {
        uint4 z4 = make_uint4(0, 0, 0, 0);
        uint4* b4 = (uint4*)Bu;                            // 16*968/8 = 1936
        for (int i = threadIdx.x; i < 1936; i += 128) b4[i] = z4;
    }
    if (threadIdx.x < 37) {
        int i = threadIdx.x, j = i - 3; bool ok = (j >= 0) && (j < KL);
        kp[0][i] = ok ? kw.k0[j] : 0.f;
        kp[1][i] = ok ? kw.k1[j] : 0.f;
        kp[2][i] = ok ? kw.k2[j] : 0.f;
    }
    if (threadIdx.x == 0) cnt = 0;
    __syncthreads();

    const int labi = blockIdx.y;
    const int label = label0 + labi;
    const unsigned short* Ab = A + (size_t)labi * a_stride;
    const int h = blockIdx.x, g = h & 7, l = h >> 3;       // 1024 x-blocks
    const int tx = threadIdx.x & 31, tz = threadIdx.x >> 5; // tz 0..3
    const int x0 = tx * 4;
    const int z0 = 16 * g + 4 * (l & 3);                   // XCD g owns z slab
    const int y0 = (l >> 2) * 4;                           // 32 y-tiles
    const int zs = (z0 + tz) * SLICE;

    // pre-issue compaction seg loads (complete under phase 1)
    const int rr_c = threadIdx.x >> 3, q0_c = threadIdx.x & 7;
    const int vrow_c = ((z0 + (rr_c >> 2)) * 128 + (y0 + (rr_c & 3))) * 128;
    unsigned pk[4];
#pragma unroll
    for (int k = 0; k < 4; ++k)
        pk[k] = seg_pack4(seg + vrow_c + 4 * (q0_c + 8 * k));

    // ---- phase 1: y-conv, T=4 outputs sliding in registers, 2-deep pipe ----
    float4 acc[6][4];                                      // [ch][t]
#pragma unroll
    for (int c = 0; c < 6; ++c)
#pragma unroll
        for (int t = 0; t < 4; ++t) acc[c][t] = make_float4(0.f, 0.f, 0.f, 0.f);

    uint2 c0 = make_uint2(0u, 0u), c1 = c0, c2 = c0;       // row j   (packed)
    uint2 n0 = c0, n1 = c0, n2 = c0;                       // row j+1
    {
        int yy = y0 - R;
        if ((unsigned)yy < 128u) {
            int base = zs + yy * 128 + x0;
            c0 = *(const uint2*)(Ab + base);
            c1 = *(const uint2*)(Ab + NV + base);
            c2 = *(const uint2*)(Ab + 2 * NV + base);
        }
        int yn = y0 + 1 - R;
        if ((unsigned)yn < 128u) {
            int base = zs + yn * 128 + x0;
            n0 = *(const uint2*)(Ab + base);
            n1 = *(const uint2*)(Ab + NV + base);
            n2 = *(const uint2*)(Ab + 2 * NV + base);
        }
    }
    for (int j = 0; j < 34; ++j) {                         // window: 4 outs + 30
        uint2 f0 = make_uint2(0u, 0u), f1 = f0, f2 = f0;
        int yy = y0 + j + 2 - R;                           // uniform per block
        if (j < 32 && (unsigned)yy < 128u) {
            int base = zs + yy * 128 + x0;
            f0 = *(const uint2*)(Ab + base);
            f1 = *(const uint2*)(Ab + NV + base);
            f2 = *(const uint2*)(Ab + 2 * NV + base);
        }
        float4 a0 = bf4_to_f4(c0), a1 = bf4_to_f4(c1), a2 = bf4_to_f4(c2);
#pragma unroll
        for (int t = 0; t < 4; ++t) {
            int i = j - t + 3;
            float w0 = kp[0][i], w1 = kp[1][i], w2 = kp[2][i];
            fma4(acc[0][t], w0, a0);
            fma4(acc[1][t], w1, a0);
            fma4(acc[2][t], w2, a0);
            fma4(acc[3][t], w0, a1);
            fma4(acc[4][t], w1, a1);
            fma4(acc[5][t], w0, a2);
        }
        c0 = n0; c1 = n1; c2 = n2;
        n0 = f0; n1 = f1; n2 = f2;
    }
#pragma unroll
    for (int t = 0; t < 4; ++t) {
        const int row = tz * 4 + t;                        // row = 4*zsub + ysub
#pragma unroll
        for (int c = 0; c < 6; ++c) {
            uint2 pv = make_uint2(pack_bf2(acc[c][t].x, acc[c][t].y),
                                  pack_bf2(acc[c][t].z, acc[c][t].w));
            *reinterpret_cast<uint2*>(Bu + row * RSTRIDE + c * CSTRIDE + 16 + x0) = pv;
        }
    }

    // ---- compaction: ballot-based, 1 atomic per wave per step ----
    {
        const int lane = threadIdx.x & 63;
        const unsigned long long below_mask = (1ull << lane) - 1ull;
#pragma unroll
        for (int k = 0; k < 4; ++k) {
            const unsigned w = pk[k];
#pragma unroll
            for (int t = 0; t < 4; ++t) {
                const int sv = (int)((w >> (8 * t)) & 255u);
                const int x = 4 * (q0_c + 8 * k) + t;
                const bool mt = (sv == label);
                const bool zt = !mt && (sv < 1 || sv > 8) &&
                                (((x & 7) + 1) == label);
                const bool pred = mt | zt;
                unsigned long long b = __ballot(pred);
                int base = 0;
                if (lane == 0 && b)
                    base = atomicAdd(&cnt, __popcll(b));
                base = __shfl(base, 0);
                if (pred) {
                    int pos = base + __popcll(b & below_mask);
                    if (pos < LCAP)
                        lst[pos] = (unsigned short)((rr_c << 7) | x |
                                                    (zt ? 0x8000 : 0));
                }
            }
        }
    }

    __syncthreads();

    // ---- phase 2: sparse x-conv + epilogue (or zero-store) ----
    const int total = cnt;
    if (total <= LCAP) {
        for (int e = threadIdx.x; e < total; e += 128) {
            int ent = lst[e];
            int rr = (ent >> 7) & 15, x = ent & 127;
            if (ent & 0x8000) zero_voxel(rr, x, z0, y0, out);
            else do_voxel(Bu, rr, x, z0, y0, out, kw);
        }
    } else {
        // adversarial-density fallback: dense masked sweep (same math)
        for (int e = threadIdx.x; e < 2048; e += 128) {
            int rr = e >> 7, x = e & 127;
            int z2 = z0 + (rr >> 2), y2 = y0 + (rr & 3);
            int sv = (int)seg[(z2 * 128 + y2) * 128 + x] & 255;
            if (sv == label)
                do_voxel(Bu, rr, x, z0, y0, out, kw);
            else if ((sv < 1 || sv > 8) && (((x & 7) + 1) == label))
                zero_voxel(rr, x, z0, y0, out);
        }
    }
}

__global__ __launch_bounds__(256) void seg_to_u8(const int* __restrict__ seg,
                                                 unsigned char* __restrict__ seg8) {
    const int t = blockIdx.x * 256 + threadIdx.x;          // 2048 blocks
    const int4 s = ((const int4*)seg)[t];
    ((uchar4*)seg8)[t] = make_uchar4((unsigned char)s.x, (unsigned char)s.y,
                                     (unsigned char)s.z, (unsigned char)s.w);
}

extern "C" void kernel_launch(void* const* d_in, const int* in_sizes, int n_in,
                              void* d_out, int out_size, void* d_ws, size_t ws_size,
                              hipStream_t stream) {
    const int* seg = (const int*)d_in[0];
    // d_in[1] (coords) unused: math is translation-invariant.
    float* out = (float*)d_out;
    unsigned short* A = (unsigned short*)d_ws;             // bf16 A planes
    const size_t AVOL = (size_t)3 * NV;                    // u16 elements/label

    Kw kw;
    double gg[KL], S = 0.0;
    for (int j = 0; j < KL; ++j) { double d = j - R; gg[j] = exp(-0.5 * d * d / 25.0); S += gg[j]; }
    for (int j = 0; j < KL; ++j) {
        double gn = gg[j] / S, d = j - R;
        kw.k0[j] = (float)gn;
        kw.k1[j] = (float)(-d * gn);   // conv kernel k1 evaluated at (Z - t) = -d
        kw.k2[j] = (float)(d * d * gn);
    }

    // No memset: pass_yx writes every output voxel exactly once across labels.

    const size_t need_all = 8 * AVOL * sizeof(unsigned short) + NV;  // A_all + seg8
    const size_t need_one = AVOL * sizeof(unsigned short) + NV;

    if (ws_size >= need_all) {
        // 3-dispatch path: labels batched in blockIdx.y, tile-major in x.
        unsigned char* seg8 = (unsigned char*)d_ws + 8 * AVOL * sizeof(unsigned short);
        seg_to_u8<<<dim3(2048), dim3(256), 0, stream>>>(seg, seg8);
        pass_z_t<unsigned char><<<dim3(512, 8), dim3(256), 0, stream>>>(
            seg8, A, 1, AVOL, kw);
        pass_yx<unsigned char><<<dim3(1024, 8), dim3(128), 0, stream>>>(
            A, seg8, out, 1, AVOL, kw);
    } else if (ws_size >= need_one) {
        unsigned char* seg8 = (unsigned char*)d_ws + AVOL * sizeof(unsigned short);
        seg_to_u8<<<dim3(2048), dim3(256), 0, stream>>>(seg, seg8);
        for (int label = 1; label <= 8; ++label) {
            pass_z_t<unsigned char><<<dim3(512, 1), dim3(256), 0, stream>>>(
                seg8, A, label, 0, kw);
            pass_yx<unsigned char><<<dim3(1024, 1), dim3(128), 0, stream>>>(
                A, seg8, out, label, 0, kw);
        }
    } else {
        for (int label = 1; label <= 8; ++label) {
            pass_z_t<int><<<dim3(512, 1), dim3(256), 0, stream>>>(
                seg, A, label, 0, kw);
            pass_yx<int><<<dim3(1024, 1), dim3(128), 0, stream>>>(
                A, seg, out, label, 0, kw);
        }
    }
}